// Round 10
// baseline (209.965 us; speedup 1.0000x reference)
//
#include <hip/hip_runtime.h>

#define T_DIM 720
#define B_DIM 50000

#define OFF_SEAS (T_DIM * B_DIM)                  /* 36,000,000 */
#define SEAS_ROWS 727
#define OFF_MSLD (OFF_SEAS + SEAS_ROWS * B_DIM)   /* 72,350,000 */
#define N_MSLD 718

#define NBLK 782                                  /* ceil(50000/64) 1-wave blocks */
#define NW NBLK
#define PAD_ROWS 8                                /* warm-up rows -8..-1 */
#define LN2_SQ 0.4804530139182014f                /* (ln 2)^2 */

// Wave64 sum via DPP: row_shr 1/2/4/8, row_bcast 15/31. Result in lane 63.
__device__ __forceinline__ float dpp_sum64(float v) {
#define DPP_ADD_STAGE(CTRL, RMASK)                                             \
  v += __int_as_float(__builtin_amdgcn_update_dpp(0, __float_as_int(v),        \
                                                  CTRL, RMASK, 0xf, false));
  DPP_ADD_STAGE(0x111, 0xf)  // row_shr:1
  DPP_ADD_STAGE(0x112, 0xf)  // row_shr:2
  DPP_ADD_STAGE(0x114, 0xf)  // row_shr:4
  DPP_ADD_STAGE(0x118, 0xf)  // row_shr:8
  DPP_ADD_STAGE(0x142, 0xa)  // row_bcast:15
  DPP_ADD_STAGE(0x143, 0xc)  // row_bcast:31
#undef DPP_ADD_STAGE
  return v;
}

// Prefetch group G (rows 1+7G .. 7+7G, clamped) into QB (NT: read-once).
#define PREFETCH(QB, G)                                                        \
  {                                                                            \
    int tp = 1 + 7 * (G);                                                      \
    _Pragma("unroll") for (int j = 0; j < 7; ++j) {                            \
      int r = tp + j;                                                          \
      r = r > 719 ? 719 : r;                                                   \
      QB[j] = __builtin_nontemporal_load(&train[r * B_DIM + bc]);              \
    }                                                                          \
  }

// Compute NS steps of group data in QB into SQC (no reduction here).
// Entirely branchless: store cursors lp/sp advance by strd (0 for invalid
// lanes, which park on a dump address). Phases expose ILP; the only true
// serial chain is the NS chained lev-FMAs.
#define ESRNN_COMPUTE(QB, SQC, NS)                                             \
  {                                                                            \
    float xds[7], nlv[7], llv[7];                                              \
    _Pragma("unroll") for (int j = 0; j < (NS); ++j)                           \
        xds[j] = __fdividef(QB[j], buf[j]);                                    \
    nlv[0] = fmaf(lsm, xds[0], olm * lev);                                     \
    _Pragma("unroll") for (int j = 1; j < (NS); ++j)                           \
        nlv[j] = fmaf(lsm, xds[j], olm * nlv[j - 1]);                          \
    _Pragma("unroll") for (int j = 0; j < (NS); ++j)                           \
        llv[j] = __log2f(nlv[j]);                                              \
    _Pragma("unroll") for (int j = 0; j < (NS); ++j)                           \
        buf[j] = fmaf(ssm, __fdividef(QB[j], nlv[j]), osm * buf[j]);           \
    _Pragma("unroll") for (int j = 0; j < (NS); ++j) {                         \
      *lp = nlv[j];                                                            \
      *sp = buf[j];                                                            \
      lp += strd;                                                              \
      sp += strd;                                                              \
    }                                                                          \
    {                                                                          \
      float ld0 = llv[0] - llev;                                               \
      float d0 = ld0 - pld;                                                    \
      SQC[0] = valid ? d0 * d0 : 0.0f;                                         \
      float ldp = ld0;                                                         \
      _Pragma("unroll") for (int j = 1; j < (NS); ++j) {                       \
        float ld = llv[j] - llv[j - 1];                                        \
        float d = ld - ldp;                                                    \
        SQC[j] = valid ? d * d : 0.0f;                                         \
        ldp = ld;                                                              \
      }                                                                        \
      pld = ldp;                                                               \
    }                                                                          \
    llev = llv[(NS)-1];                                                        \
    lev = nlv[(NS)-1];                                                         \
  }

// Reduce NS rows of SQP (previous group) and store via the pp cursor
// (lanes != 63 write the dump; cursor stride 0 there). Branchless.
#define ESRNN_REDUCE(SQP, NS)                                                  \
  {                                                                            \
    _Pragma("unroll") for (int j = 0; j < (NS); ++j)                           \
        SQP[j] = dpp_sum64(SQP[j]);                                            \
    _Pragma("unroll") for (int j = 0; j < (NS); ++j) {                         \
      *pp = SQP[j];                                                            \
      pp += pstrd;                                                             \
    }                                                                          \
  }

#define ESRNN_GROUP(QB, QP, SQC, SQP)                                          \
  {                                                                            \
    PREFETCH(QP, g + 2)                                                        \
    ESRNN_COMPUTE(QB, SQC, 7)                                                  \
    ESRNN_REDUCE(SQP, 7)                                                       \
    ++g;                                                                       \
  }

__global__ __launch_bounds__(64) void esrnn_main(
    const float* __restrict__ train,        // (720, B)
    const float* __restrict__ lev_sms,      // (B,)
    const float* __restrict__ seas_sms,     // (B,)
    const float* __restrict__ init_seas_in, // (B, 7)
    float* __restrict__ levs_out,           // (720, B)
    float* __restrict__ seas_out,           // (727, B)
    float* __restrict__ ws)                 // [PAD+718 rows][NW] + dump
{
  int b = blockIdx.x * 64 + threadIdx.x;
  bool valid = (b < B_DIM);
  int bc = valid ? b : (B_DIM - 1);
  int lane = threadIdx.x;
  int wid = blockIdx.x;

  float lsm = 1.0f / (1.0f + __expf(-lev_sms[bc]));
  float ssm = 1.0f / (1.0f + __expf(-seas_sms[bc]));
  float olm = 1.0f - lsm;
  float osm = 1.0f - ssm;

  float is[7];
#pragma unroll
  for (int j = 0; j < 7; ++j) is[j] = __expf(init_seas_in[bc * 7 + j]);

  float seas0 = is[0];
  float x0 = train[bc];
  float lev = __fdividef(x0, seas0);

  if (valid) {
    levs_out[b] = lev;
#pragma unroll
    for (int j = 0; j < 7; ++j) seas_out[j * B_DIM + b] = is[j];
    seas_out[7 * B_DIM + b] = seas0;
  }

  float buf[7];
#pragma unroll
  for (int j = 0; j < 6; ++j) buf[j] = is[j + 1];
  buf[6] = seas0;

  float llev = __log2f(lev);  // log2 units; ln2^2 applied in reduce kernel
  float pld = 0.0f;

  // Branchless store cursors. Invalid / non-63 lanes park on dump (stride 0).
  float* dump = ws + (size_t)(PAD_ROWS + N_MSLD) * NW;
  float* lp = valid ? (levs_out + (size_t)B_DIM + b) : (dump + lane);
  float* sp = valid ? (seas_out + (size_t)8 * B_DIM + b) : (dump + 64 + lane);
  int strd = valid ? B_DIM : 0;
  float* pp = (lane == 63) ? (ws + wid) : (dump + 128 + lane);
  int pstrd = (lane == 63) ? NW : 0;

  float xa[7], xb[7], xc[7], sqa[7], sqb[7], sqc[7];
#pragma unroll
  for (int j = 0; j < 7; ++j) sqc[j] = 0.0f;  // group "-1": lands in pad rows

  int g = 0;
  PREFETCH(xa, 0)
  PREFETCH(xb, 1)

  // 102 groups = 34 x 3-phase rotation; reduce is deferred one group so the
  // DPP trees interleave with the next group's divides/FMA chain.
  for (int k = 0; k < 34; ++k) {
    ESRNN_GROUP(xa, xc, sqa, sqc)
    ESRNN_GROUP(xb, xa, sqb, sqa)
    ESRNN_GROUP(xc, xb, sqc, sqb)
  }

  // Drain: reduce group 101 (sqc), compute+reduce tail group 102 (5 steps).
  ESRNN_REDUCE(sqc, 7)
  ESRNN_COMPUTE(xa, sqa, 5)
  ESRNN_REDUCE(sqa, 5)
}

__global__ __launch_bounds__(64) void esrnn_reduce2(
    const float* __restrict__ ws, float* __restrict__ msld) {
  const float* partial = ws + (size_t)PAD_ROWS * NW;
  int row = blockIdx.x;  // 0..717
  int lane = threadIdx.x;
  float s = 0.0f;
  for (int i = lane; i < NW; i += 64) s += partial[row * NW + i];
  float tot = dpp_sum64(s);
  if (lane == 63) msld[row] = tot * (LN2_SQ / (float)B_DIM);
}

extern "C" void kernel_launch(void* const* d_in, const int* in_sizes, int n_in,
                              void* d_out, int out_size, void* d_ws,
                              size_t ws_size, hipStream_t stream) {
  const float* train = (const float*)d_in[0];
  const float* lev_sms = (const float*)d_in[1];
  const float* seas_sms = (const float*)d_in[2];
  const float* init_seas = (const float*)d_in[3];

  float* out = (float*)d_out;
  float* levs = out;
  float* seas = out + OFF_SEAS;
  float* msld = out + OFF_MSLD;
  float* ws = (float*)d_ws;  // (8+718)*782*4 + dump ~= 2.3 MB

  esrnn_main<<<NBLK, 64, 0, stream>>>(train, lev_sms, seas_sms, init_seas,
                                      levs, seas, ws);
  esrnn_reduce2<<<N_MSLD, 64, 0, stream>>>(ws, msld);
}

// Round 11
// 134.216 us; speedup vs baseline: 1.5644x; 1.5644x over previous
//
#include <hip/hip_runtime.h>

#define T_DIM 720
#define B_DIM 50000

#define OFF_SEAS (T_DIM * B_DIM)                  /* 36,000,000 */
#define SEAS_ROWS 727
#define OFF_MSLD (OFF_SEAS + SEAS_ROWS * B_DIM)   /* 72,350,000 */
#define N_MSLD 718

#define NBLK 782                                  /* ceil(50000/64) 1-wave blocks */
#define NW NBLK
#define LN2_SQ 0.4804530139182014f                /* (ln 2)^2 */

// Wave64 sum via DPP: row_shr 1/2/4/8, row_bcast 15/31. Result in lane 63.
__device__ __forceinline__ float dpp_sum64(float v) {
#define DPP_ADD_STAGE(CTRL, RMASK)                                             \
  v += __int_as_float(__builtin_amdgcn_update_dpp(0, __float_as_int(v),        \
                                                  CTRL, RMASK, 0xf, false));
  DPP_ADD_STAGE(0x111, 0xf)  // row_shr:1
  DPP_ADD_STAGE(0x112, 0xf)  // row_shr:2
  DPP_ADD_STAGE(0x114, 0xf)  // row_shr:4
  DPP_ADD_STAGE(0x118, 0xf)  // row_shr:8
  DPP_ADD_STAGE(0x142, 0xa)  // row_bcast:15
  DPP_ADD_STAGE(0x143, 0xc)  // row_bcast:31
#undef DPP_ADD_STAGE
  return v;
}

// Prefetch group G (rows 1+7G .. 7+7G, clamped) into QB. Regular loads:
// train (144 MB) is L3-resident across replays; NT would force ~900-cyc HBM.
#define PREFETCH(QB, G)                                                        \
  {                                                                            \
    int tp = 1 + 7 * (G);                                                      \
    _Pragma("unroll") for (int j = 0; j < 7; ++j) {                            \
      int r = tp + j;                                                          \
      r = r > 719 ? 719 : r;                                                   \
      QB[j] = train[r * B_DIM + bc];                                           \
    }                                                                          \
  }

// Compute NS steps from QB into SQC (reduction deferred). Phases expose ILP;
// the only true serial chain is the NS chained lev-FMAs.
#define ESRNN_COMPUTE(QB, SQC, NS)                                             \
  {                                                                            \
    float xds[7], nlv[7], llv[7];                                              \
    _Pragma("unroll") for (int j = 0; j < (NS); ++j)                           \
        xds[j] = __fdividef(QB[j], buf[j]);                                    \
    nlv[0] = fmaf(lsm, xds[0], olm * lev);                                     \
    _Pragma("unroll") for (int j = 1; j < (NS); ++j)                           \
        nlv[j] = fmaf(lsm, xds[j], olm * nlv[j - 1]);                          \
    _Pragma("unroll") for (int j = 0; j < (NS); ++j)                           \
        llv[j] = __log2f(nlv[j]);                                              \
    _Pragma("unroll") for (int j = 0; j < (NS); ++j)                           \
        buf[j] = fmaf(ssm, __fdividef(QB[j], nlv[j]), osm * buf[j]);           \
    if (valid) {                                                               \
      _Pragma("unroll") for (int j = 0; j < (NS); ++j) {                       \
        *(float*)(lbase + boff + (unsigned)(j * B_DIM * 4)) = nlv[j];          \
        *(float*)(sbase + boff + (unsigned)(j * B_DIM * 4)) = buf[j];          \
      }                                                                        \
    }                                                                          \
    boff += (NS)*B_DIM * 4;                                                    \
    {                                                                          \
      float ld0 = llv[0] - llev;                                               \
      float d0 = ld0 - pld;                                                    \
      SQC[0] = valid ? d0 * d0 : 0.0f;                                         \
      float ldp = ld0;                                                         \
      _Pragma("unroll") for (int j = 1; j < (NS); ++j) {                       \
        float ld = llv[j] - llv[j - 1];                                        \
        float d = ld - ldp;                                                    \
        SQC[j] = valid ? d * d : 0.0f;                                         \
        ldp = ld;                                                              \
      }                                                                        \
      pld = ldp;                                                               \
    }                                                                          \
    llev = llv[(NS)-1];                                                        \
    lev = nlv[(NS)-1];                                                         \
  }

// Reduce NS rows of SQ (a previous group) and store partials for rows
// TB+0..TB+NS-1 from lane 63 (exec-masked; rows < 0 skipped).
#define ESRNN_REDUCE(SQ, NS, TB)                                               \
  {                                                                            \
    _Pragma("unroll") for (int j = 0; j < (NS); ++j) SQ[j] = dpp_sum64(SQ[j]); \
    if (lane == 63) {                                                          \
      _Pragma("unroll") for (int j = 0; j < (NS); ++j) {                       \
        int row = (TB) + j;                                                    \
        if (row >= 0) partial[row * NW + wid] = SQ[j];                         \
      }                                                                        \
    }                                                                          \
  }

// One group: prefetch 3 ahead, compute this group, reduce the PREVIOUS
// group's squares (their DPP trees interleave with this group's divides).
#define ESRNN_GROUP(QB, QP, SQC, SQP)                                          \
  {                                                                            \
    PREFETCH(QP, g + 3)                                                        \
    ESRNN_COMPUTE(QB, SQC, 7)                                                  \
    ESRNN_REDUCE(SQP, 7, 7 * g - 8)                                            \
    ++g;                                                                       \
  }

__global__ __launch_bounds__(64) void esrnn_main(
    const float* __restrict__ train,        // (720, B)
    const float* __restrict__ lev_sms,      // (B,)
    const float* __restrict__ seas_sms,     // (B,)
    const float* __restrict__ init_seas_in, // (B, 7)
    float* __restrict__ levs_out,           // (720, B)
    float* __restrict__ seas_out,           // (727, B)
    float* __restrict__ partial)            // (718, NW) per-wave partials
{
  int b = blockIdx.x * 64 + threadIdx.x;
  bool valid = (b < B_DIM);
  int bc = valid ? b : (B_DIM - 1);
  int lane = threadIdx.x;
  int wid = blockIdx.x;

  float lsm = 1.0f / (1.0f + __expf(-lev_sms[bc]));
  float ssm = 1.0f / (1.0f + __expf(-seas_sms[bc]));
  float olm = 1.0f - lsm;
  float osm = 1.0f - ssm;

  float is[7];
#pragma unroll
  for (int j = 0; j < 7; ++j) is[j] = __expf(init_seas_in[bc * 7 + j]);

  float seas0 = is[0];
  float x0 = train[bc];
  float lev = __fdividef(x0, seas0);

  if (valid) {
    levs_out[b] = lev;
#pragma unroll
    for (int j = 0; j < 7; ++j) seas_out[j * B_DIM + b] = is[j];
    seas_out[7 * B_DIM + b] = seas0;
  }

  float buf[7];
#pragma unroll
  for (int j = 0; j < 6; ++j) buf[j] = is[j + 1];
  buf[6] = seas0;

  float llev = __log2f(lev);  // log2 units; ln2^2 applied in reduce kernel
  float pld = 0.0f;

  // saddr-form store bases + shared per-lane byte offset.
  char* lbase = (char*)levs_out + (size_t)B_DIM * 4;      // row t=1
  char* sbase = (char*)seas_out + (size_t)8 * B_DIM * 4;  // row t+7=8
  unsigned int boff = (unsigned int)b * 4u;

  float xa[7], xb[7], xc[7], xd[7], sqa[7], sqb[7];
#pragma unroll
  for (int j = 0; j < 7; ++j) sqb[j] = 0.0f;  // group "-1" (rows < 0, skipped)

  int g = 0;
  PREFETCH(xa, 0)
  PREFETCH(xb, 1)
  PREFETCH(xc, 2)

  // 100 groups = 25 x 4-buffer rotation (prefetch distance 3), sq ping-pong.
  for (int k = 0; k < 25; ++k) {
    ESRNN_GROUP(xa, xd, sqa, sqb)
    ESRNN_GROUP(xb, xa, sqb, sqa)
    ESRNN_GROUP(xc, xb, sqa, sqb)
    ESRNN_GROUP(xd, xc, sqb, sqa)
  }
  // groups 100, 101
  ESRNN_GROUP(xa, xd, sqa, sqb)
  ESRNN_GROUP(xb, xa, sqb, sqa)

  // Drain: reduce group 101 (sqb, rows 706..712), then tail group 102
  // (t=715..719 in xc), rows 713..717.
  ESRNN_REDUCE(sqb, 7, 706)
  ESRNN_COMPUTE(xc, sqa, 5)
  ESRNN_REDUCE(sqa, 5, 713)
}

__global__ __launch_bounds__(64) void esrnn_reduce2(
    const float* __restrict__ partial, float* __restrict__ msld) {
  int row = blockIdx.x;  // 0..717
  int lane = threadIdx.x;
  float s = 0.0f;
  for (int i = lane; i < NW; i += 64) s += partial[row * NW + i];
  float tot = dpp_sum64(s);
  if (lane == 63) msld[row] = tot * (LN2_SQ / (float)B_DIM);
}

extern "C" void kernel_launch(void* const* d_in, const int* in_sizes, int n_in,
                              void* d_out, int out_size, void* d_ws,
                              size_t ws_size, hipStream_t stream) {
  const float* train = (const float*)d_in[0];
  const float* lev_sms = (const float*)d_in[1];
  const float* seas_sms = (const float*)d_in[2];
  const float* init_seas = (const float*)d_in[3];

  float* out = (float*)d_out;
  float* levs = out;
  float* seas = out + OFF_SEAS;
  float* msld = out + OFF_MSLD;
  float* partial = (float*)d_ws;  // 718*782*4 ~= 2.25 MB

  esrnn_main<<<NBLK, 64, 0, stream>>>(train, lev_sms, seas_sms, init_seas,
                                      levs, seas, partial);
  esrnn_reduce2<<<N_MSLD, 64, 0, stream>>>(partial, msld);
}

// Round 12
// 124.888 us; speedup vs baseline: 1.6812x; 1.0747x over previous
//
#include <hip/hip_runtime.h>

#define T_DIM 720
#define B_DIM 50000

#define OFF_SEAS (T_DIM * B_DIM)                  /* 36,000,000 */
#define SEAS_ROWS 727
#define OFF_MSLD (OFF_SEAS + SEAS_ROWS * B_DIM)   /* 72,350,000 */
#define N_MSLD 718

#define NBLK 782                                  /* ceil(50000/64) 1-wave blocks */
#define NW NBLK
#define LN2_SQ 0.4804530139182014f                /* (ln 2)^2 */

// Wave64 sum via DPP: row_shr 1/2/4/8, row_bcast 15/31. Result in lane 63.
__device__ __forceinline__ float dpp_sum64(float v) {
#define DPP_ADD_STAGE(CTRL, RMASK)                                             \
  v += __int_as_float(__builtin_amdgcn_update_dpp(0, __float_as_int(v),        \
                                                  CTRL, RMASK, 0xf, false));
  DPP_ADD_STAGE(0x111, 0xf)  // row_shr:1
  DPP_ADD_STAGE(0x112, 0xf)  // row_shr:2
  DPP_ADD_STAGE(0x114, 0xf)  // row_shr:4
  DPP_ADD_STAGE(0x118, 0xf)  // row_shr:8
  DPP_ADD_STAGE(0x142, 0xa)  // row_bcast:15
  DPP_ADD_STAGE(0x143, 0xc)  // row_bcast:31
#undef DPP_ADD_STAGE
  return v;
}

// Prefetch group G (rows 1+7G .. 7+7G, clamped) into QB (NT: read-once stream,
// keep L2 free for the 292 MB write stream).
#define PREFETCH(QB, G)                                                        \
  {                                                                            \
    int tp = 1 + 7 * (G);                                                      \
    _Pragma("unroll") for (int j = 0; j < 7; ++j) {                            \
      int r = tp + j;                                                          \
      r = r > 719 ? 719 : r;                                                   \
      QB[j] = __builtin_nontemporal_load(&train[r * B_DIM + bc]);              \
    }                                                                          \
  }

// One group, batched ILP phases (as R9). Per-wave partials go to LDS
// (slot = row+1, so the t<2 rows land in slot 0 with no guard); the global
// partial store happens once, at kernel end, in a wave-major layout.
#define ESRNN_GROUP_N(QB, NS)                                                  \
  {                                                                            \
    float xds[7], nlv[7], llv[7];                                              \
    _Pragma("unroll") for (int j = 0; j < (NS); ++j)                           \
        xds[j] = __fdividef(QB[j], buf[j]);                                    \
    nlv[0] = fmaf(lsm, xds[0], olm * lev);                                     \
    _Pragma("unroll") for (int j = 1; j < (NS); ++j)                           \
        nlv[j] = fmaf(lsm, xds[j], olm * nlv[j - 1]);                          \
    _Pragma("unroll") for (int j = 0; j < (NS); ++j)                           \
        llv[j] = __log2f(nlv[j]);                                              \
    _Pragma("unroll") for (int j = 0; j < (NS); ++j)                           \
        buf[j] = fmaf(ssm, __fdividef(QB[j], nlv[j]), osm * buf[j]);           \
    if (valid) {                                                               \
      _Pragma("unroll") for (int j = 0; j < (NS); ++j) {                       \
        *(float*)(lbase + boff + (unsigned)(j * B_DIM * 4)) = nlv[j];          \
        *(float*)(sbase + boff + (unsigned)(j * B_DIM * 4)) = buf[j];          \
      }                                                                        \
    }                                                                          \
    boff += (NS)*B_DIM * 4;                                                    \
    float sqv[7];                                                              \
    {                                                                          \
      float ld0 = llv[0] - llev;                                               \
      float d0 = ld0 - pld;                                                    \
      sqv[0] = valid ? d0 * d0 : 0.0f;                                         \
      float ldp = ld0;                                                         \
      _Pragma("unroll") for (int j = 1; j < (NS); ++j) {                       \
        float ld = llv[j] - llv[j - 1];                                        \
        float d = ld - ldp;                                                    \
        sqv[j] = valid ? d * d : 0.0f;                                         \
        ldp = ld;                                                              \
      }                                                                        \
      pld = ldp;                                                               \
    }                                                                          \
    llev = llv[(NS)-1];                                                        \
    lev = nlv[(NS)-1];                                                         \
    _Pragma("unroll") for (int j = 0; j < (NS); ++j)                           \
        sqv[j] = dpp_sum64(sqv[j]);                                            \
    if (lane == 63) {                                                          \
      int tb = 1 + 7 * g;                                                      \
      _Pragma("unroll") for (int j = 0; j < (NS); ++j)                         \
          lds_p[tb + j - 1] = sqv[j];                                          \
    }                                                                          \
  }

#define ESRNN_GROUP(QB, QP)                                                    \
  {                                                                            \
    PREFETCH(QP, g + 2)                                                        \
    ESRNN_GROUP_N(QB, 7)                                                       \
    ++g;                                                                       \
  }

__global__ __launch_bounds__(64) void esrnn_main(
    const float* __restrict__ train,        // (720, B)
    const float* __restrict__ lev_sms,      // (B,)
    const float* __restrict__ seas_sms,     // (B,)
    const float* __restrict__ init_seas_in, // (B, 7)
    float* __restrict__ levs_out,           // (720, B)
    float* __restrict__ seas_out,           // (727, B)
    float* __restrict__ partial)            // (NW, 718) wave-major partials
{
  __shared__ float lds_p[720];  // slot r+1 holds row r; slot 0 = dummy (t<2)

  int b = blockIdx.x * 64 + threadIdx.x;
  bool valid = (b < B_DIM);
  int bc = valid ? b : (B_DIM - 1);
  int lane = threadIdx.x;
  int wid = blockIdx.x;

  float lsm = 1.0f / (1.0f + __expf(-lev_sms[bc]));
  float ssm = 1.0f / (1.0f + __expf(-seas_sms[bc]));
  float olm = 1.0f - lsm;
  float osm = 1.0f - ssm;

  float is[7];
#pragma unroll
  for (int j = 0; j < 7; ++j) is[j] = __expf(init_seas_in[bc * 7 + j]);

  float seas0 = is[0];
  float x0 = train[bc];
  float lev = __fdividef(x0, seas0);

  if (valid) {
    levs_out[b] = lev;
#pragma unroll
    for (int j = 0; j < 7; ++j) seas_out[j * B_DIM + b] = is[j];
    seas_out[7 * B_DIM + b] = seas0;
  }

  float buf[7];
#pragma unroll
  for (int j = 0; j < 6; ++j) buf[j] = is[j + 1];
  buf[6] = seas0;

  float llev = __log2f(lev);  // log2 units; ln2^2 applied in reduce kernel
  float pld = 0.0f;

  // saddr-form store bases + shared per-lane byte offset.
  char* lbase = (char*)levs_out + (size_t)B_DIM * 4;      // row t=1
  char* sbase = (char*)seas_out + (size_t)8 * B_DIM * 4;  // row t+7=8
  unsigned int boff = (unsigned int)b * 4u;

  float xa[7], xb[7], xc[7];
  int g = 0;
  PREFETCH(xa, 0)
  PREFETCH(xb, 1)

  // 102 groups = 34 x 3-phase buffer rotation, prefetching 2 groups ahead.
  for (int k = 0; k < 34; ++k) {
    ESRNN_GROUP(xa, xc)
    ESRNN_GROUP(xb, xa)
    ESRNN_GROUP(xc, xb)
  }

  // tail: t = 715..719 in xa (group 102), buf pos 0..4
  ESRNN_GROUP_N(xa, 5)

  // Flush this wave's 718 row-partials to its contiguous private strip.
  __syncthreads();  // single-wave block: just drains LDS writes (lgkmcnt)
  float* mystrip = partial + (size_t)wid * N_MSLD;
  for (int i = lane; i < N_MSLD; i += 64) mystrip[i] = lds_p[i + 1];
}

__global__ __launch_bounds__(64) void esrnn_reduce2(
    const float* __restrict__ partial, float* __restrict__ msld) {
  int row = blockIdx.x;  // 0..717
  int lane = threadIdx.x;
  float s = 0.0f;
  for (int i = lane; i < NW; i += 64)
    s += partial[(size_t)i * N_MSLD + row];
  float tot = dpp_sum64(s);
  if (lane == 63) msld[row] = tot * (LN2_SQ / (float)B_DIM);
}

extern "C" void kernel_launch(void* const* d_in, const int* in_sizes, int n_in,
                              void* d_out, int out_size, void* d_ws,
                              size_t ws_size, hipStream_t stream) {
  const float* train = (const float*)d_in[0];
  const float* lev_sms = (const float*)d_in[1];
  const float* seas_sms = (const float*)d_in[2];
  const float* init_seas = (const float*)d_in[3];

  float* out = (float*)d_out;
  float* levs = out;
  float* seas = out + OFF_SEAS;
  float* msld = out + OFF_MSLD;
  float* partial = (float*)d_ws;  // NW*718*4 ~= 2.25 MB, wave-major

  esrnn_main<<<NBLK, 64, 0, stream>>>(train, lev_sms, seas_sms, init_seas,
                                      levs, seas, partial);
  esrnn_reduce2<<<N_MSLD, 64, 0, stream>>>(partial, msld);
}

// Round 13
// 119.703 us; speedup vs baseline: 1.7541x; 1.0433x over previous
//
#include <hip/hip_runtime.h>

#define T_DIM 720
#define B_DIM 50000

#define OFF_SEAS (T_DIM * B_DIM)                  /* 36,000,000 */
#define SEAS_ROWS 727
#define OFF_MSLD (OFF_SEAS + SEAS_ROWS * B_DIM)   /* 72,350,000 */
#define N_MSLD 718

#define NBLK 782                                  /* ceil(50000/64) 1-wave blocks */
#define NW NBLK
#define LN2_SQ 0.4804530139182014f                /* (ln 2)^2 */

// Wave64 sum via DPP: row_shr 1/2/4/8, row_bcast 15/31. Result in lane 63.
__device__ __forceinline__ float dpp_sum64(float v) {
#define DPP_ADD_STAGE(CTRL, RMASK)                                             \
  v += __int_as_float(__builtin_amdgcn_update_dpp(0, __float_as_int(v),        \
                                                  CTRL, RMASK, 0xf, false));
  DPP_ADD_STAGE(0x111, 0xf)  // row_shr:1
  DPP_ADD_STAGE(0x112, 0xf)  // row_shr:2
  DPP_ADD_STAGE(0x114, 0xf)  // row_shr:4
  DPP_ADD_STAGE(0x118, 0xf)  // row_shr:8
  DPP_ADD_STAGE(0x142, 0xa)  // row_bcast:15
  DPP_ADD_STAGE(0x143, 0xc)  // row_bcast:31
#undef DPP_ADD_STAGE
  return v;
}

// Issue loads for group G (rows 1+7G .. 7+7G, clamped) into QB. No pin here.
#define PREFETCH(QB, G)                                                        \
  {                                                                            \
    int tp = 1 + 7 * (G);                                                      \
    _Pragma("unroll") for (int j = 0; j < 7; ++j) {                            \
      int r = tp + j;                                                          \
      r = r > 719 ? 719 : r;                                                   \
      QB[j] = __builtin_nontemporal_load(&train[r * B_DIM + bc]);              \
    }                                                                          \
  }

// Zero-cost register pin: forces QB's loads to be materialized by this point
// (one group AFTER issue, one group BEFORE use) — prevents the scheduler from
// sinking the loads to their use points, preserving real prefetch distance.
#define PIN7(QB)                                                               \
  asm volatile("" : "+v"(QB[0]), "+v"(QB[1]), "+v"(QB[2]), "+v"(QB[3]),        \
                    "+v"(QB[4]), "+v"(QB[5]), "+v"(QB[6]));

// One group, batched ILP phases (R9/R12 structure). Per-wave partials to LDS.
#define ESRNN_GROUP_N(QB, NS)                                                  \
  {                                                                            \
    float xds[7], nlv[7], llv[7];                                              \
    _Pragma("unroll") for (int j = 0; j < (NS); ++j)                           \
        xds[j] = __fdividef(QB[j], buf[j]);                                    \
    nlv[0] = fmaf(lsm, xds[0], olm * lev);                                     \
    _Pragma("unroll") for (int j = 1; j < (NS); ++j)                           \
        nlv[j] = fmaf(lsm, xds[j], olm * nlv[j - 1]);                          \
    _Pragma("unroll") for (int j = 0; j < (NS); ++j)                           \
        llv[j] = __log2f(nlv[j]);                                              \
    _Pragma("unroll") for (int j = 0; j < (NS); ++j)                           \
        buf[j] = fmaf(ssm, __fdividef(QB[j], nlv[j]), osm * buf[j]);           \
    if (valid) {                                                               \
      _Pragma("unroll") for (int j = 0; j < (NS); ++j) {                       \
        *(float*)(lbase + boff + (unsigned)(j * B_DIM * 4)) = nlv[j];          \
        *(float*)(sbase + boff + (unsigned)(j * B_DIM * 4)) = buf[j];          \
      }                                                                        \
    }                                                                          \
    boff += (NS)*B_DIM * 4;                                                    \
    float sqv[7];                                                              \
    {                                                                          \
      float ld0 = llv[0] - llev;                                               \
      float d0 = ld0 - pld;                                                    \
      sqv[0] = valid ? d0 * d0 : 0.0f;                                         \
      float ldp = ld0;                                                         \
      _Pragma("unroll") for (int j = 1; j < (NS); ++j) {                       \
        float ld = llv[j] - llv[j - 1];                                        \
        float d = ld - ldp;                                                    \
        sqv[j] = valid ? d * d : 0.0f;                                         \
        ldp = ld;                                                              \
      }                                                                        \
      pld = ldp;                                                               \
    }                                                                          \
    llev = llv[(NS)-1];                                                        \
    lev = nlv[(NS)-1];                                                         \
    _Pragma("unroll") for (int j = 0; j < (NS); ++j)                           \
        sqv[j] = dpp_sum64(sqv[j]);                                            \
    if (lane == 63) {                                                          \
      int tb = 1 + 7 * g;                                                      \
      _Pragma("unroll") for (int j = 0; j < (NS); ++j)                         \
          lds_p[tb + j - 1] = sqv[j];                                          \
    }                                                                          \
  }

// Body(g): issue loads for g+2 into QLD, pin QPIN (holds g+1, issued one
// group ago), consume QB (holds g, pinned one group ago).
#define ESRNN_GROUP(QB, QPIN, QLD)                                             \
  {                                                                            \
    PREFETCH(QLD, g + 2)                                                       \
    PIN7(QPIN)                                                                 \
    ESRNN_GROUP_N(QB, 7)                                                       \
    ++g;                                                                       \
  }

__global__ __launch_bounds__(64) void esrnn_main(
    const float* __restrict__ train,        // (720, B)
    const float* __restrict__ lev_sms,      // (B,)
    const float* __restrict__ seas_sms,     // (B,)
    const float* __restrict__ init_seas_in, // (B, 7)
    float* __restrict__ levs_out,           // (720, B)
    float* __restrict__ seas_out,           // (727, B)
    float* __restrict__ partial)            // (NW, 718) wave-major partials
{
  __shared__ float lds_p[720];  // slot r+1 holds row r; slot 0 = dummy (t<2)

  int b = blockIdx.x * 64 + threadIdx.x;
  bool valid = (b < B_DIM);
  int bc = valid ? b : (B_DIM - 1);
  int lane = threadIdx.x;
  int wid = blockIdx.x;

  float lsm = 1.0f / (1.0f + __expf(-lev_sms[bc]));
  float ssm = 1.0f / (1.0f + __expf(-seas_sms[bc]));
  float olm = 1.0f - lsm;
  float osm = 1.0f - ssm;

  float is[7];
#pragma unroll
  for (int j = 0; j < 7; ++j) is[j] = __expf(init_seas_in[bc * 7 + j]);

  float seas0 = is[0];
  float x0 = train[bc];
  float lev = __fdividef(x0, seas0);

  if (valid) {
    levs_out[b] = lev;
#pragma unroll
    for (int j = 0; j < 7; ++j) seas_out[j * B_DIM + b] = is[j];
    seas_out[7 * B_DIM + b] = seas0;
  }

  float buf[7];
#pragma unroll
  for (int j = 0; j < 6; ++j) buf[j] = is[j + 1];
  buf[6] = seas0;

  float llev = __log2f(lev);  // log2 units; ln2^2 applied in reduce kernel
  float pld = 0.0f;

  // saddr-form store bases + shared per-lane byte offset.
  char* lbase = (char*)levs_out + (size_t)B_DIM * 4;      // row t=1
  char* sbase = (char*)seas_out + (size_t)8 * B_DIM * 4;  // row t+7=8
  unsigned int boff = (unsigned int)b * 4u;

  float xa[7], xb[7], xc[7];
  int g = 0;
  PREFETCH(xa, 0)
  PREFETCH(xb, 1)

  // 102 groups = 34 x 3-buffer rotation. Pin each buffer one group after its
  // loads were issued, one group before its consumption.
  for (int k = 0; k < 34; ++k) {
    ESRNN_GROUP(xa, xb, xc)
    ESRNN_GROUP(xb, xc, xa)
    ESRNN_GROUP(xc, xa, xb)
  }

  // tail: t = 715..719 in xa (group 102; pinned during body 101), buf 0..4
  ESRNN_GROUP_N(xa, 5)

  // Flush this wave's 718 row-partials to its contiguous private strip.
  __syncthreads();  // single-wave block: just drains LDS writes
  float* mystrip = partial + (size_t)wid * N_MSLD;
  for (int i = lane; i < N_MSLD; i += 64) mystrip[i] = lds_p[i + 1];
}

__global__ __launch_bounds__(64) void esrnn_reduce2(
    const float* __restrict__ partial, float* __restrict__ msld) {
  int row = blockIdx.x;  // 0..717
  int lane = threadIdx.x;
  float s = 0.0f;
  for (int i = lane; i < NW; i += 64)
    s += partial[(size_t)i * N_MSLD + row];
  float tot = dpp_sum64(s);
  if (lane == 63) msld[row] = tot * (LN2_SQ / (float)B_DIM);
}

extern "C" void kernel_launch(void* const* d_in, const int* in_sizes, int n_in,
                              void* d_out, int out_size, void* d_ws,
                              size_t ws_size, hipStream_t stream) {
  const float* train = (const float*)d_in[0];
  const float* lev_sms = (const float*)d_in[1];
  const float* seas_sms = (const float*)d_in[2];
  const float* init_seas = (const float*)d_in[3];

  float* out = (float*)d_out;
  float* levs = out;
  float* seas = out + OFF_SEAS;
  float* msld = out + OFF_MSLD;
  float* partial = (float*)d_ws;  // NW*718*4 ~= 2.25 MB, wave-major

  esrnn_main<<<NBLK, 64, 0, stream>>>(train, lev_sms, seas_sms, init_seas,
                                      levs, seas, partial);
  esrnn_reduce2<<<N_MSLD, 64, 0, stream>>>(partial, msld);
}

// Round 14
// 116.174 us; speedup vs baseline: 1.8073x; 1.0304x over previous
//
#include <hip/hip_runtime.h>

#define T_DIM 720
#define B_DIM 50000

#define OFF_SEAS (T_DIM * B_DIM)                  /* 36,000,000 */
#define SEAS_ROWS 727
#define OFF_MSLD (OFF_SEAS + SEAS_ROWS * B_DIM)   /* 72,350,000 */
#define N_MSLD 718

#define NBLK 782                                  /* ceil(50000/64) 1-wave blocks */
#define NW NBLK
#define LN2_SQ 0.4804530139182014f                /* (ln 2)^2 */

// Wave64 sum via DPP: row_shr 1/2/4/8, row_bcast 15/31. Result in lane 63.
__device__ __forceinline__ float dpp_sum64(float v) {
#define DPP_ADD_STAGE(CTRL, RMASK)                                             \
  v += __int_as_float(__builtin_amdgcn_update_dpp(0, __float_as_int(v),        \
                                                  CTRL, RMASK, 0xf, false));
  DPP_ADD_STAGE(0x111, 0xf)  // row_shr:1
  DPP_ADD_STAGE(0x112, 0xf)  // row_shr:2
  DPP_ADD_STAGE(0x114, 0xf)  // row_shr:4
  DPP_ADD_STAGE(0x118, 0xf)  // row_shr:8
  DPP_ADD_STAGE(0x142, 0xa)  // row_bcast:15
  DPP_ADD_STAGE(0x143, 0xc)  // row_bcast:31
#undef DPP_ADD_STAGE
  return v;
}

// Issue loads for group G (rows 1+7G .. 7+7G, clamped) into QB. No pin here.
#define PREFETCH(QB, G)                                                        \
  {                                                                            \
    int tp = 1 + 7 * (G);                                                      \
    _Pragma("unroll") for (int j = 0; j < 7; ++j) {                            \
      int r = tp + j;                                                          \
      r = r > 719 ? 719 : r;                                                   \
      QB[j] = __builtin_nontemporal_load(&train[r * B_DIM + bc]);              \
    }                                                                          \
  }

// Zero-cost register pin: forces QB's loads to be materialized here (two
// group-times after issue, one body before use) — keeps prefetch distance
// real without early vmcnt drains.
#define PIN7(QB)                                                               \
  asm volatile("" : "+v"(QB[0]), "+v"(QB[1]), "+v"(QB[2]), "+v"(QB[3]),        \
                    "+v"(QB[4]), "+v"(QB[5]), "+v"(QB[6]));

// One group, batched ILP phases (R9/R12 structure). Per-wave partials to LDS.
#define ESRNN_GROUP_N(QB, NS)                                                  \
  {                                                                            \
    float xds[7], nlv[7], llv[7];                                              \
    _Pragma("unroll") for (int j = 0; j < (NS); ++j)                           \
        xds[j] = __fdividef(QB[j], buf[j]);                                    \
    nlv[0] = fmaf(lsm, xds[0], olm * lev);                                     \
    _Pragma("unroll") for (int j = 1; j < (NS); ++j)                           \
        nlv[j] = fmaf(lsm, xds[j], olm * nlv[j - 1]);                          \
    _Pragma("unroll") for (int j = 0; j < (NS); ++j)                           \
        llv[j] = __log2f(nlv[j]);                                              \
    _Pragma("unroll") for (int j = 0; j < (NS); ++j)                           \
        buf[j] = fmaf(ssm, __fdividef(QB[j], nlv[j]), osm * buf[j]);           \
    if (valid) {                                                               \
      _Pragma("unroll") for (int j = 0; j < (NS); ++j) {                       \
        *(float*)(lbase + boff + (unsigned)(j * B_DIM * 4)) = nlv[j];          \
        *(float*)(sbase + boff + (unsigned)(j * B_DIM * 4)) = buf[j];          \
      }                                                                        \
    }                                                                          \
    boff += (NS)*B_DIM * 4;                                                    \
    float sqv[7];                                                              \
    {                                                                          \
      float ld0 = llv[0] - llev;                                               \
      float d0 = ld0 - pld;                                                    \
      sqv[0] = valid ? d0 * d0 : 0.0f;                                         \
      float ldp = ld0;                                                         \
      _Pragma("unroll") for (int j = 1; j < (NS); ++j) {                       \
        float ld = llv[j] - llv[j - 1];                                        \
        float d = ld - ldp;                                                    \
        sqv[j] = valid ? d * d : 0.0f;                                         \
        ldp = ld;                                                              \
      }                                                                        \
      pld = ldp;                                                               \
    }                                                                          \
    llev = llv[(NS)-1];                                                        \
    lev = nlv[(NS)-1];                                                         \
    _Pragma("unroll") for (int j = 0; j < (NS); ++j)                           \
        sqv[j] = dpp_sum64(sqv[j]);                                            \
    if (lane == 63) {                                                          \
      int tb = 1 + 7 * g;                                                      \
      _Pragma("unroll") for (int j = 0; j < (NS); ++j)                         \
          lds_p[tb + j - 1] = sqv[j];                                          \
    }                                                                          \
  }

// Body(g): issue loads for group g+3 into QLD; pin QPIN (issued at body g-2,
// consumed at body g+1); consume QB (issued at body g-3, pinned at body g-1).
#define ESRNN_GROUP(QB, QPIN, QLD)                                             \
  {                                                                            \
    PREFETCH(QLD, g + 3)                                                       \
    PIN7(QPIN)                                                                 \
    ESRNN_GROUP_N(QB, 7)                                                       \
    ++g;                                                                       \
  }

__global__ __launch_bounds__(64) void esrnn_main(
    const float* __restrict__ train,        // (720, B)
    const float* __restrict__ lev_sms,      // (B,)
    const float* __restrict__ seas_sms,     // (B,)
    const float* __restrict__ init_seas_in, // (B, 7)
    float* __restrict__ levs_out,           // (720, B)
    float* __restrict__ seas_out,           // (727, B)
    float* __restrict__ partial)            // (NW, 718) wave-major partials
{
  __shared__ float lds_p[720];  // slot r+1 holds row r; slot 0 = dummy (t<2)

  int b = blockIdx.x * 64 + threadIdx.x;
  bool valid = (b < B_DIM);
  int bc = valid ? b : (B_DIM - 1);
  int lane = threadIdx.x;
  int wid = blockIdx.x;

  float lsm = 1.0f / (1.0f + __expf(-lev_sms[bc]));
  float ssm = 1.0f / (1.0f + __expf(-seas_sms[bc]));
  float olm = 1.0f - lsm;
  float osm = 1.0f - ssm;

  float is[7];
#pragma unroll
  for (int j = 0; j < 7; ++j) is[j] = __expf(init_seas_in[bc * 7 + j]);

  float seas0 = is[0];
  float x0 = train[bc];
  float lev = __fdividef(x0, seas0);

  if (valid) {
    levs_out[b] = lev;
#pragma unroll
    for (int j = 0; j < 7; ++j) seas_out[j * B_DIM + b] = is[j];
    seas_out[7 * B_DIM + b] = seas0;
  }

  float buf[7];
#pragma unroll
  for (int j = 0; j < 6; ++j) buf[j] = is[j + 1];
  buf[6] = seas0;

  float llev = __log2f(lev);  // log2 units; ln2^2 applied in reduce kernel
  float pld = 0.0f;

  // saddr-form store bases + shared per-lane byte offset.
  char* lbase = (char*)levs_out + (size_t)B_DIM * 4;      // row t=1
  char* sbase = (char*)seas_out + (size_t)8 * B_DIM * 4;  // row t+7=8
  unsigned int boff = (unsigned int)b * 4u;

  float xa[7], xb[7], xc[7], xd[7];
  int g = 0;
  PREFETCH(xa, 0)
  PREFETCH(xb, 1)
  PREFETCH(xc, 2)

  // 100 groups = 25 x 4-buffer rotation, prefetch distance 3.
  // Each buffer: issued at body g, pinned at body g+2, consumed at body g+3.
  for (int k = 0; k < 25; ++k) {
    ESRNN_GROUP(xa, xb, xd)
    ESRNN_GROUP(xb, xc, xa)
    ESRNN_GROUP(xc, xd, xb)
    ESRNN_GROUP(xd, xa, xc)
  }
  // groups 100, 101 (their prefetches clamp to row 719; harmless)
  ESRNN_GROUP(xa, xb, xd)
  ESRNN_GROUP(xb, xc, xa)

  // tail: t = 715..719 = group 102 in xc (pinned during body 101), buf 0..4
  ESRNN_GROUP_N(xc, 5)

  // Flush this wave's 718 row-partials to its contiguous private strip.
  __syncthreads();  // single-wave block: just drains LDS writes
  float* mystrip = partial + (size_t)wid * N_MSLD;
  for (int i = lane; i < N_MSLD; i += 64) mystrip[i] = lds_p[i + 1];
}

__global__ __launch_bounds__(64) void esrnn_reduce2(
    const float* __restrict__ partial, float* __restrict__ msld) {
  int row = blockIdx.x;  // 0..717
  int lane = threadIdx.x;
  float s = 0.0f;
  for (int i = lane; i < NW; i += 64)
    s += partial[(size_t)i * N_MSLD + row];
  float tot = dpp_sum64(s);
  if (lane == 63) msld[row] = tot * (LN2_SQ / (float)B_DIM);
}

extern "C" void kernel_launch(void* const* d_in, const int* in_sizes, int n_in,
                              void* d_out, int out_size, void* d_ws,
                              size_t ws_size, hipStream_t stream) {
  const float* train = (const float*)d_in[0];
  const float* lev_sms = (const float*)d_in[1];
  const float* seas_sms = (const float*)d_in[2];
  const float* init_seas = (const float*)d_in[3];

  float* out = (float*)d_out;
  float* levs = out;
  float* seas = out + OFF_SEAS;
  float* msld = out + OFF_MSLD;
  float* partial = (float*)d_ws;  // NW*718*4 ~= 2.25 MB, wave-major

  esrnn_main<<<NBLK, 64, 0, stream>>>(train, lev_sms, seas_sms, init_seas,
                                      levs, seas, partial);
  esrnn_reduce2<<<N_MSLD, 64, 0, stream>>>(partial, msld);
}